// Round 8
// baseline (215.492 us; speedup 1.0000x reference)
//
#include <hip/hip_runtime.h>

#define ALPHA 0.90483741803595957f

// ---------------------------------------------------------------------------
// K0: fold avgpool into conv kernels.
// W1eff[oc][ch][u][v] (4x2x8x8): conv1 5x5 pad2 + pool4  => 8x8 stride-4 conv
// W2eff[oc][ch][u][v] (8x4x4x4): conv2 3x3 pad1 + pool2  => 4x4 stride-2 conv
// ---------------------------------------------------------------------------
__global__ void prep_weights(const float* __restrict__ w1, const float* __restrict__ w2,
                             float* __restrict__ w1e, float* __restrict__ w2e) {
    int idx = blockIdx.x * 256 + threadIdx.x;
    if (idx < 512) {
        int v = idx & 7, u = (idx >> 3) & 7, ch = (idx >> 6) & 1, oc = idx >> 7;
        float s = 0.f;
        for (int a = 0; a < 5; ++a) {
            int i = u - a; if (i < 0 || i > 3) continue;
            for (int b = 0; b < 5; ++b) {
                int j = v - b; if (j < 0 || j > 3) continue;
                s += w1[((oc * 2 + ch) * 5 + a) * 5 + b];
            }
        }
        w1e[idx] = s * (1.f / 16.f);
    } else if (idx < 1024) {
        int k = idx - 512;
        int v = k & 3, u = (k >> 2) & 3, ch = (k >> 4) & 3, oc = k >> 6;
        float s = 0.f;
        for (int a = 0; a < 3; ++a) {
            int i = u - a; if (i < 0 || i > 1) continue;
            for (int b = 0; b < 3; ++b) {
                int j = v - b; if (j < 0 || j > 1) continue;
                s += w2[((oc * 4 + ch) * 3 + a) * 3 + b];
            }
        }
        w2e[k] = s * 0.25f;
    }
}

// ---------------------------------------------------------------------------
// K1: conv1 + pool4 via 8x8/stride-4 effective kernel.  (unchanged, proven)
// ---------------------------------------------------------------------------
__global__ __launch_bounds__(256) void conv1_pool(const float* __restrict__ x,
                                                  const float* __restrict__ w1e,
                                                  float* __restrict__ y1) {
    __shared__ __align__(16) float tile[4][2][36][36];  // 41472 B
    int tid = threadIdx.x;

    float4* t4 = (float4*)&tile[0][0][0][0];
    #pragma unroll
    for (int k = 0; k < 11; ++k) {
        int i = tid + k * 256;
        if (i < 2592) t4[i] = make_float4(0.f, 0.f, 0.f, 0.f);
    }
    __syncthreads();

    int li = tid >> 6, pos = tid & 63;
    long gi = (long)blockIdx.x * 4 + li;            // bt index, < 12800
    const float* src = x + gi * 2048;               // 2ch*32*32
    #pragma unroll
    for (int k = 0; k < 8; ++k) {
        int e = k * 256 + pos * 4;                  // 16B-aligned
        float4 d = *(const float4*)(src + e);
        int ch = e >> 10, rem = e & 1023, r = rem >> 5, c = rem & 31;
        float* dst = &tile[li][ch][r + 2][c + 2];
        dst[0] = d.x; dst[1] = d.y; dst[2] = d.z; dst[3] = d.w;
    }
    __syncthreads();

    int p = pos >> 3, q = pos & 7;
    float acc0 = 0.f, acc1 = 0.f, acc2 = 0.f, acc3 = 0.f;
    #pragma unroll
    for (int ch = 0; ch < 2; ++ch) {
        #pragma unroll
        for (int r = 0; r < 8; ++r) {
            const float* row = &tile[li][ch][4 * p + r][4 * q];  // 16B aligned
            float4 a = *(const float4*)row;
            float4 b = *(const float4*)(row + 4);
            float in[8] = {a.x, a.y, a.z, a.w, b.x, b.y, b.z, b.w};
            #pragma unroll
            for (int c = 0; c < 8; ++c) {
                float xi = in[c];
                acc0 += w1e[((0 * 2 + ch) * 8 + r) * 8 + c] * xi;  // uniform -> s_load
                acc1 += w1e[((1 * 2 + ch) * 8 + r) * 8 + c] * xi;
                acc2 += w1e[((2 * 2 + ch) * 8 + r) * 8 + c] * xi;
                acc3 += w1e[((3 * 2 + ch) * 8 + r) * 8 + c] * xi;
            }
        }
    }
    float* dst = y1 + gi * 256 + pos;   // [bt][oc][p][q]
    dst[0] = acc0; dst[64] = acc1; dst[128] = acc2; dst[192] = acc3;
}

// ---------------------------------------------------------------------------
// K2: fused scan1 + conv2/pool2 + scan2, TWO blocks per b (256 blocks total),
// one wave each, barrier-free, read-ahead pipelined (R7 structure).
// NEW vs R7: the conv2 output space is split by oc-half across 2 blocks.
// Stage-1 scan is duplicated in both blocks (identical inputs -> identical
// spikes, deterministic, ~24 VALU/t -- cheap) so there is NO cross-block
// communication. Each lane now computes ONE conv output (64 FMA/t instead of
// 128), one scan2 chain, one store -> per-wave issue/latency per t roughly
// halves, and the grid covers all 256 CUs instead of 128.
// All FP chains (scan1, ch-major conv chain per output, scan2) bit-identical
// to prior rounds -> absmax stays 0.
// ---------------------------------------------------------------------------
#define READW(base, Q)                                                        \
    {                                                                         \
        _Pragma("unroll")                                                     \
        for (int rr = 0; rr < 4; ++rr) {                                      \
            _Pragma("unroll")                                                 \
            for (int cc = 0; cc < 4; ++cc) {                                  \
                float4 tq = *(const float4*)((base) + rr * 40 + cc * 4);      \
                int o = (rr * 4 + cc) * 4;                                    \
                Q[o + 0] = tq.x; Q[o + 1] = tq.y;                             \
                Q[o + 2] = tq.z; Q[o + 3] = tq.w;                             \
            }                                                                 \
        }                                                                     \
    }

#define SCAN1_WRITE(in0, in1, in2, in3, d0, d1)                               \
    {                                                                         \
        v10 = ALPHA * v10 + (in0); v20 = ALPHA * v20 + v10;                   \
        float s0 = (v20 >= 1.f) ? 1.f : 0.f; v20 -= s0;                       \
        v11 = ALPHA * v11 + (in1); v21 = ALPHA * v21 + v11;                   \
        float s1 = (v21 >= 1.f) ? 1.f : 0.f; v21 -= s1;                       \
        v12 = ALPHA * v12 + (in2); v22 = ALPHA * v22 + v12;                   \
        float s2 = (v22 >= 1.f) ? 1.f : 0.f; v22 -= s2;                       \
        v13 = ALPHA * v13 + (in3); v23 = ALPHA * v23 + v13;                   \
        float s3 = (v23 >= 1.f) ? 1.f : 0.f; v23 -= s3;                       \
        float4 sp = make_float4(s0, s1, s2, s3);                              \
        *(float4*)(d0) = sp;                                                  \
        *(float4*)(d1) = sp;                                                  \
    }

#define CONV_SCAN2_STORE(Q, t)                                                \
    {                                                                         \
        float acca = 0.f;                                                     \
        _Pragma("unroll")                                                     \
        for (int ch = 0; ch < 4; ++ch) {                                      \
            _Pragma("unroll")                                                 \
            for (int rr = 0; rr < 4; ++rr) {                                  \
                _Pragma("unroll")                                             \
                for (int cc = 0; cc < 4; ++cc) {                              \
                    acca += wa[ch * 16 + rr * 4 + cc] *                       \
                            Q[(rr * 4 + cc) * 4 + ch];                        \
                }                                                             \
            }                                                                 \
        }                                                                     \
        w1a = ALPHA * w1a + acca; w2a = ALPHA * w2a + w1a;                    \
        float sa = (w2a >= 1.f) ? 1.f : 0.f; w2a -= sa;                       \
        dst[(t) * 128] = sa;                                                  \
    }

__global__ __launch_bounds__(64, 1) void fused_wave(const float* __restrict__ y1,
                                                    const float* __restrict__ w2e,
                                                    float* __restrict__ s2g) {
    __shared__ float tE[808];   // even-t spikes: copy A @0, copy B @404
    __shared__ float tO[808];   // odd-t  spikes: same layout
    int lane = threadIdx.x;
    int b = blockIdx.x >> 1;    // batch element
    int h = blockIdx.x & 1;     // oc-half: 0 -> oc 0..3, 1 -> oc 4..7

    #pragma unroll
    for (int k = 0; k < 13; ++k) {
        int i = lane + k * 64;
        if (i < 808) { tE[i] = 0.f; tO[i] = 0.f; }
    }

    // stage-1 mapping: f = 64k + lane -> (ch=k, r=lane>>3, c=lane&7)
    int r1 = lane >> 3, c1 = lane & 7;
    int posq = ((r1 + 1) * 10 + (c1 + 1)) * 4;
    float* wE0 = &tE[posq];
    float* wE1 = &tE[404 + posq];
    float* wO0 = &tO[posq];
    float* wO1 = &tO[404 + posq];

    // conv2 mapping: f2 = h*64 + lane -> (oc = h*4 + (lane>>4), p, q)
    int oc = h * 4 + (lane >> 4), p = (lane >> 2) & 3, q = lane & 3;

    // conv2 weights resident in VGPRs (pinned below)
    float wa[64];
    #pragma unroll
    for (int k = 0; k < 16; ++k) {
        float4 ta = *(const float4*)(w2e + oc * 64 + k * 4);
        wa[k * 4 + 0] = ta.x; wa[k * 4 + 1] = ta.y;
        wa[k * 4 + 2] = ta.z; wa[k * 4 + 3] = ta.w;
    }

    int rbq = ((2 * p) * 10 + 2 * q) * 4 + ((p & 1) ? 404 : 0);
    const float* rbE = &tE[rbq];
    const float* rbO = &tO[rbq];

    // ---- PIN weights into VGPRs: outlaw rematerialization/reload ----
    #pragma unroll
    for (int k = 0; k < 64; ++k) {
        asm volatile("" : "+v"(wa[k]));
    }

    const float* src = y1 + (long)b * 25600 + lane;        // y1[b][t][f], f = 64k+lane
    float* dst = s2g + (long)b * 12800 + h * 64 + lane;    // s2[bt][f2]

    // y1 pipeline: x=t0 (consumed in prologue), c=t(2i+1),t(2i+2), p=t(2i+3),t(2i+4)
    float x0  = src[0],    x1  = src[64],   x2  = src[128],  x3  = src[192];
    float c10 = src[256],  c11 = src[320],  c12 = src[384],  c13 = src[448];
    float c20 = src[512],  c21 = src[576],  c22 = src[640],  c23 = src[704];
    float p10 = src[768],  p11 = src[832],  p12 = src[896],  p13 = src[960];
    float p20 = src[1024], p21 = src[1088], p22 = src[1152], p23 = src[1216];

    float v10 = 0.f, v20 = 0.f, v11 = 0.f, v21 = 0.f;
    float v12 = 0.f, v22 = 0.f, v13 = 0.f, v23 = 0.f;
    float w1a = 0.f, w2a = 0.f;

    float qa[64], qb[64];   // read-ahead window registers

    // prologue: scan1(0) -> E, then issue window(0) reads -> qa
    SCAN1_WRITE(x0, x1, x2, x3, wE0, wE1)
    READW(rbE, qa)

    for (int i = 0; i < 49; ++i) {
        // deep global prefetch: t = 2i+5, 2i+6 (consumed 2 iterations later)
        int t5 = 2 * i + 5, t6 = 2 * i + 6;
        const float* a5 = src + (t5 < 100 ? t5 * 256 : 0);
        const float* a6 = src + (t6 < 100 ? t6 * 256 : 0);
        float n10 = a5[0], n11 = a5[64], n12 = a5[128], n13 = a5[192];
        float n20 = a6[0], n21 = a6[64], n22 = a6[128], n23 = a6[192];

        // 1: scan1(2i+1) -> write O
        SCAN1_WRITE(c10, c11, c12, c13, wO0, wO1)
        // 2: issue window(2i+1) reads -> qb (consumed after conv(2i))
        READW(rbO, qb)
        // 3: conv(2i) on qa (already resident -> no lgkm stall) + scan2 + store
        CONV_SCAN2_STORE(qa, 2 * i)
        // 4: scan1(2i+2) -> write E (prior E reads long since issued: WAR safe)
        SCAN1_WRITE(c20, c21, c22, c23, wE0, wE1)
        // 5: issue window(2i+2) reads -> qa (consumed next body)
        READW(rbE, qa)
        // 6: conv(2i+1) on qb + scan2 + store
        CONV_SCAN2_STORE(qb, 2 * i + 1)

        // rotate y1 pipeline
        c10 = p10; c11 = p11; c12 = p12; c13 = p13;
        c20 = p20; c21 = p21; c22 = p22; c23 = p23;
        p10 = n10; p11 = n11; p12 = n12; p13 = n13;
        p20 = n20; p21 = n21; p22 = n22; p23 = n23;
    }

    // epilogue: after i=48 loop, c1 = y1[99]; qa holds window(98)
    SCAN1_WRITE(c10, c11, c12, c13, wO0, wO1)   // scan1(99) -> O
    READW(rbO, qb)                               // window(99) -> qb
    CONV_SCAN2_STORE(qa, 98)
    CONV_SCAN2_STORE(qb, 99)
}

// ---------------------------------------------------------------------------
// K3: out[bt][o] = sum_f s2[bt][f] * lin_w[o][f].  One wave per bt.
// (bit-exact lineage from R0/R2: same pairing + shfl_down tree)
// ---------------------------------------------------------------------------
__global__ __launch_bounds__(256) void linear_out(const float* __restrict__ s2,
                                                  const float* __restrict__ lw,
                                                  float* __restrict__ out) {
    int tid = threadIdx.x;
    long bt = (long)blockIdx.x * 4 + (tid >> 6);
    int lane = tid & 63;
    float2 v = *(const float2*)(s2 + bt * 128 + lane * 2);
    float w00 = lw[lane * 2], w01 = lw[lane * 2 + 1];
    float w10 = lw[128 + lane * 2], w11 = lw[128 + lane * 2 + 1];
    float a0 = v.x * w00 + v.y * w01;
    float a1 = v.x * w10 + v.y * w11;
    #pragma unroll
    for (int off = 32; off; off >>= 1) {
        a0 += __shfl_down(a0, off);
        a1 += __shfl_down(a1, off);
    }
    if (lane == 0) { out[bt * 2] = a0; out[bt * 2 + 1] = a1; }
}

extern "C" void kernel_launch(void* const* d_in, const int* in_sizes, int n_in,
                              void* d_out, int out_size, void* d_ws, size_t ws_size,
                              hipStream_t stream) {
    const float* x  = (const float*)d_in[0];   // [128,100,2,32,32]
    const float* w1 = (const float*)d_in[1];   // [4,2,5,5]
    const float* w2 = (const float*)d_in[2];   // [8,4,3,3]
    const float* lw = (const float*)d_in[3];   // [2,128]
    float* out = (float*)d_out;                // [128,100,2]

    float* ws   = (float*)d_ws;
    float* w1e  = ws;                          // 512 floats
    float* w2e  = ws + 512;                    // 512 floats
    float* y1   = ws + 1024;                   // 12800*256 floats = 13.1 MB
    float* s2g  = y1 + 3276800;                // 12800*128 floats = 6.55 MB

    prep_weights<<<4, 256, 0, stream>>>(w1, w2, w1e, w2e);
    conv1_pool<<<3200, 256, 0, stream>>>(x, w1e, y1);
    fused_wave<<<256, 64, 0, stream>>>(y1, w2e, s2g);
    linear_out<<<3200, 256, 0, stream>>>(s2g, lw, out);
}

// Round 9
// 201.279 us; speedup vs baseline: 1.0706x; 1.0706x over previous
//
#include <hip/hip_runtime.h>

#define ALPHA 0.90483741803595957f

// ---------------------------------------------------------------------------
// K0: fold avgpool into conv kernels.
// W1eff[oc][ch][u][v] (4x2x8x8): conv1 5x5 pad2 + pool4  => 8x8 stride-4 conv
// W2eff[oc][ch][u][v] (8x4x4x4): conv2 3x3 pad1 + pool2  => 4x4 stride-2 conv
// ---------------------------------------------------------------------------
__global__ void prep_weights(const float* __restrict__ w1, const float* __restrict__ w2,
                             float* __restrict__ w1e, float* __restrict__ w2e) {
    int idx = blockIdx.x * 256 + threadIdx.x;
    if (idx < 512) {
        int v = idx & 7, u = (idx >> 3) & 7, ch = (idx >> 6) & 1, oc = idx >> 7;
        float s = 0.f;
        for (int a = 0; a < 5; ++a) {
            int i = u - a; if (i < 0 || i > 3) continue;
            for (int b = 0; b < 5; ++b) {
                int j = v - b; if (j < 0 || j > 3) continue;
                s += w1[((oc * 2 + ch) * 5 + a) * 5 + b];
            }
        }
        w1e[idx] = s * (1.f / 16.f);
    } else if (idx < 1024) {
        int k = idx - 512;
        int v = k & 3, u = (k >> 2) & 3, ch = (k >> 4) & 3, oc = k >> 6;
        float s = 0.f;
        for (int a = 0; a < 3; ++a) {
            int i = u - a; if (i < 0 || i > 1) continue;
            for (int b = 0; b < 3; ++b) {
                int j = v - b; if (j < 0 || j > 1) continue;
                s += w2[((oc * 4 + ch) * 3 + a) * 3 + b];
            }
        }
        w2e[k] = s * 0.25f;
    }
}

// ---------------------------------------------------------------------------
// K1: conv1 + pool4 via 8x8/stride-4 effective kernel.  (unchanged, proven)
// ---------------------------------------------------------------------------
__global__ __launch_bounds__(256) void conv1_pool(const float* __restrict__ x,
                                                  const float* __restrict__ w1e,
                                                  float* __restrict__ y1) {
    __shared__ __align__(16) float tile[4][2][36][36];  // 41472 B
    int tid = threadIdx.x;

    float4* t4 = (float4*)&tile[0][0][0][0];
    #pragma unroll
    for (int k = 0; k < 11; ++k) {
        int i = tid + k * 256;
        if (i < 2592) t4[i] = make_float4(0.f, 0.f, 0.f, 0.f);
    }
    __syncthreads();

    int li = tid >> 6, pos = tid & 63;
    long gi = (long)blockIdx.x * 4 + li;            // bt index, < 12800
    const float* src = x + gi * 2048;               // 2ch*32*32
    #pragma unroll
    for (int k = 0; k < 8; ++k) {
        int e = k * 256 + pos * 4;                  // 16B-aligned
        float4 d = *(const float4*)(src + e);
        int ch = e >> 10, rem = e & 1023, r = rem >> 5, c = rem & 31;
        float* dst = &tile[li][ch][r + 2][c + 2];
        dst[0] = d.x; dst[1] = d.y; dst[2] = d.z; dst[3] = d.w;
    }
    __syncthreads();

    int p = pos >> 3, q = pos & 7;
    float acc0 = 0.f, acc1 = 0.f, acc2 = 0.f, acc3 = 0.f;
    #pragma unroll
    for (int ch = 0; ch < 2; ++ch) {
        #pragma unroll
        for (int r = 0; r < 8; ++r) {
            const float* row = &tile[li][ch][4 * p + r][4 * q];  // 16B aligned
            float4 a = *(const float4*)row;
            float4 b = *(const float4*)(row + 4);
            float in[8] = {a.x, a.y, a.z, a.w, b.x, b.y, b.z, b.w};
            #pragma unroll
            for (int c = 0; c < 8; ++c) {
                float xi = in[c];
                acc0 += w1e[((0 * 2 + ch) * 8 + r) * 8 + c] * xi;  // uniform -> s_load
                acc1 += w1e[((1 * 2 + ch) * 8 + r) * 8 + c] * xi;
                acc2 += w1e[((2 * 2 + ch) * 8 + r) * 8 + c] * xi;
                acc3 += w1e[((3 * 2 + ch) * 8 + r) * 8 + c] * xi;
            }
        }
    }
    float* dst = y1 + gi * 256 + pos;   // [bt][oc][p][q]
    dst[0] = acc0; dst[64] = acc1; dst[128] = acc2; dst[192] = acc3;
}

// ---------------------------------------------------------------------------
// K2: fused scan1 + conv2/pool2 + scan2, one wave per b (128 blocks, R7 shape),
// barrier-free, read-ahead pipelined.
// NEW vs R7/R8: the ENTIRE y1 slice for b (100x256 floats = 102.4 KB) is
// staged into LDS in the prologue (coalesced float4 bulk copy). The t-loop
// then has ZERO global loads: scan1 inputs are 4 ds_read_b32/t, read one
// body (~600cyc) ahead. Rationale: R8 falsified issue-boundedness (halving
// FMA work made it worse) -> the stall was the in-loop global y1 prefetch
// whose lead time (2 bodies) < L3/HBM latency (y1 is written by conv1_pool
// on other XCDs, so reads miss local L2). LDS removes that chain entirely.
// LDS total = 102400 + 2*3232 = 108864 B (gfx950: 160KB/CU, 1 block/CU ok).
// All FP chains bit-identical to prior rounds -> absmax stays 0.
// ---------------------------------------------------------------------------
#define READW(base, Q)                                                        \
    {                                                                         \
        _Pragma("unroll")                                                     \
        for (int rr = 0; rr < 4; ++rr) {                                      \
            _Pragma("unroll")                                                 \
            for (int cc = 0; cc < 4; ++cc) {                                  \
                float4 tq = *(const float4*)((base) + rr * 40 + cc * 4);      \
                int o = (rr * 4 + cc) * 4;                                    \
                Q[o + 0] = tq.x; Q[o + 1] = tq.y;                             \
                Q[o + 2] = tq.z; Q[o + 3] = tq.w;                             \
            }                                                                 \
        }                                                                     \
    }

#define SCAN1_WRITE(in0, in1, in2, in3, d0, d1)                               \
    {                                                                         \
        v10 = ALPHA * v10 + (in0); v20 = ALPHA * v20 + v10;                   \
        float s0 = (v20 >= 1.f) ? 1.f : 0.f; v20 -= s0;                       \
        v11 = ALPHA * v11 + (in1); v21 = ALPHA * v21 + v11;                   \
        float s1 = (v21 >= 1.f) ? 1.f : 0.f; v21 -= s1;                       \
        v12 = ALPHA * v12 + (in2); v22 = ALPHA * v22 + v12;                   \
        float s2 = (v22 >= 1.f) ? 1.f : 0.f; v22 -= s2;                       \
        v13 = ALPHA * v13 + (in3); v23 = ALPHA * v23 + v13;                   \
        float s3 = (v23 >= 1.f) ? 1.f : 0.f; v23 -= s3;                       \
        float4 sp = make_float4(s0, s1, s2, s3);                              \
        *(float4*)(d0) = sp;                                                  \
        *(float4*)(d1) = sp;                                                  \
    }

#define CONV_SCAN2_STORE(Q, t)                                                \
    {                                                                         \
        float acca = 0.f, accb = 0.f;                                         \
        _Pragma("unroll")                                                     \
        for (int ch = 0; ch < 4; ++ch) {                                      \
            _Pragma("unroll")                                                 \
            for (int rr = 0; rr < 4; ++rr) {                                  \
                _Pragma("unroll")                                             \
                for (int cc = 0; cc < 4; ++cc) {                              \
                    float xv = Q[(rr * 4 + cc) * 4 + ch];                     \
                    acca += wa[ch * 16 + rr * 4 + cc] * xv;                   \
                    accb += wb[ch * 16 + rr * 4 + cc] * xv;                   \
                }                                                             \
            }                                                                 \
        }                                                                     \
        w1a = ALPHA * w1a + acca; w2a = ALPHA * w2a + w1a;                    \
        float sa = (w2a >= 1.f) ? 1.f : 0.f; w2a -= sa;                       \
        w1b = ALPHA * w1b + accb; w2b = ALPHA * w2b + w1b;                    \
        float sb = (w2b >= 1.f) ? 1.f : 0.f; w2b -= sb;                       \
        dst[(t) * 128]      = sa;                                             \
        dst[(t) * 128 + 64] = sb;                                             \
    }

// scan-input read from the staged LDS copy: f = 64k + lane
#define LY(t, k) lds_y[(t) * 256 + (k) * 64 + lane]

__global__ __launch_bounds__(64, 1) void fused_wave(const float* __restrict__ y1,
                                                    const float* __restrict__ w2e,
                                                    float* __restrict__ s2g) {
    __shared__ float lds_y[25600];   // y1[b] slice: [t][f] 100x256 = 102400 B
    __shared__ float tE[808];        // even-t spikes: copy A @0, copy B @404
    __shared__ float tO[808];        // odd-t  spikes: same layout
    int lane = threadIdx.x;
    int b = blockIdx.x;

    #pragma unroll
    for (int k = 0; k < 13; ++k) {
        int i = lane + k * 64;
        if (i < 808) { tE[i] = 0.f; tO[i] = 0.f; }
    }

    // ---- stage the whole y1[b] slice into LDS (coalesced, groups of 20) ----
    {
        const float* gsrc = y1 + (long)b * 25600;
        #pragma unroll 20
        for (int k = 0; k < 100; ++k) {
            float4 d = *(const float4*)(gsrc + k * 256 + (lane << 2));
            *(float4*)(&lds_y[k * 256 + (lane << 2)]) = d;
        }
    }

    // stage-1 mapping: f = 64k + lane -> (ch=k, r=lane>>3, c=lane&7)
    int r1 = lane >> 3, c1 = lane & 7;
    int posq = ((r1 + 1) * 10 + (c1 + 1)) * 4;
    float* wE0 = &tE[posq];
    float* wE1 = &tE[404 + posq];
    float* wO0 = &tO[posq];
    float* wO1 = &tO[404 + posq];

    // conv2 mapping: f2a = lane -> (oc, p, q); f2b = lane + 64 -> oc+4 same (p,q)
    int oc = lane >> 4, p = (lane >> 2) & 3, q = lane & 3;

    // conv2 weights resident in VGPRs (pinned below)
    float wa[64], wb[64];
    #pragma unroll
    for (int k = 0; k < 16; ++k) {
        float4 ta = *(const float4*)(w2e + oc * 64 + k * 4);
        float4 tb = *(const float4*)(w2e + (oc + 4) * 64 + k * 4);
        wa[k * 4 + 0] = ta.x; wa[k * 4 + 1] = ta.y; wa[k * 4 + 2] = ta.z; wa[k * 4 + 3] = ta.w;
        wb[k * 4 + 0] = tb.x; wb[k * 4 + 1] = tb.y; wb[k * 4 + 2] = tb.z; wb[k * 4 + 3] = tb.w;
    }

    int rbq = ((2 * p) * 10 + 2 * q) * 4 + ((p & 1) ? 404 : 0);
    const float* rbE = &tE[rbq];
    const float* rbO = &tO[rbq];

    // ---- PIN weights into VGPRs: outlaw rematerialization/reload ----
    #pragma unroll
    for (int k = 0; k < 64; ++k) {
        asm volatile("" : "+v"(wa[k]));
        asm volatile("" : "+v"(wb[k]));
    }

    float* dst = s2g + (long)b * 12800 + lane;   // s2[bt][f]: f=lane, lane+64

    // scan-input pipeline from LDS: x=t0, c=t(2i+1),t(2i+2), p=t(2i+3),t(2i+4)
    float x0  = LY(0, 0), x1  = LY(0, 1), x2  = LY(0, 2), x3  = LY(0, 3);
    float c10 = LY(1, 0), c11 = LY(1, 1), c12 = LY(1, 2), c13 = LY(1, 3);
    float c20 = LY(2, 0), c21 = LY(2, 1), c22 = LY(2, 2), c23 = LY(2, 3);
    float p10 = LY(3, 0), p11 = LY(3, 1), p12 = LY(3, 2), p13 = LY(3, 3);
    float p20 = LY(4, 0), p21 = LY(4, 1), p22 = LY(4, 2), p23 = LY(4, 3);

    float v10 = 0.f, v20 = 0.f, v11 = 0.f, v21 = 0.f;
    float v12 = 0.f, v22 = 0.f, v13 = 0.f, v23 = 0.f;
    float w1a = 0.f, w2a = 0.f, w1b = 0.f, w2b = 0.f;

    float qa[64], qb[64];   // read-ahead window registers

    // prologue: scan1(0) -> E, then issue window(0) reads -> qa
    SCAN1_WRITE(x0, x1, x2, x3, wE0, wE1)
    READW(rbE, qa)

    for (int i = 0; i < 49; ++i) {
        // read-ahead scan inputs t = 2i+5, 2i+6 from LDS (consumed 2 iters later)
        int t5 = 2 * i + 5, t6 = 2 * i + 6;
        int o5 = (t5 < 100 ? t5 : 0), o6 = (t6 < 100 ? t6 : 0);
        float n10 = LY(o5, 0), n11 = LY(o5, 1), n12 = LY(o5, 2), n13 = LY(o5, 3);
        float n20 = LY(o6, 0), n21 = LY(o6, 1), n22 = LY(o6, 2), n23 = LY(o6, 3);

        // 1: scan1(2i+1) -> write O
        SCAN1_WRITE(c10, c11, c12, c13, wO0, wO1)
        // 2: issue window(2i+1) reads -> qb (consumed after conv(2i))
        READW(rbO, qb)
        // 3: conv(2i) on qa (already resident -> no lgkm stall) + scan2 + store
        CONV_SCAN2_STORE(qa, 2 * i)
        // 4: scan1(2i+2) -> write E (prior E reads long since issued: WAR safe)
        SCAN1_WRITE(c20, c21, c22, c23, wE0, wE1)
        // 5: issue window(2i+2) reads -> qa (consumed next body)
        READW(rbE, qa)
        // 6: conv(2i+1) on qb + scan2 + store
        CONV_SCAN2_STORE(qb, 2 * i + 1)

        // rotate scan-input pipeline
        c10 = p10; c11 = p11; c12 = p12; c13 = p13;
        c20 = p20; c21 = p21; c22 = p22; c23 = p23;
        p10 = n10; p11 = n11; p12 = n12; p13 = n13;
        p20 = n20; p21 = n21; p22 = n22; p23 = n23;
    }

    // epilogue: after i=48 loop, c1 = y1[99]; qa holds window(98)
    SCAN1_WRITE(c10, c11, c12, c13, wO0, wO1)   // scan1(99) -> O
    READW(rbO, qb)                               // window(99) -> qb
    CONV_SCAN2_STORE(qa, 98)
    CONV_SCAN2_STORE(qb, 99)
}

// ---------------------------------------------------------------------------
// K3: out[bt][o] = sum_f s2[bt][f] * lin_w[o][f].  One wave per bt.
// (bit-exact lineage from R0/R2: same pairing + shfl_down tree)
// ---------------------------------------------------------------------------
__global__ __launch_bounds__(256) void linear_out(const float* __restrict__ s2,
                                                  const float* __restrict__ lw,
                                                  float* __restrict__ out) {
    int tid = threadIdx.x;
    long bt = (long)blockIdx.x * 4 + (tid >> 6);
    int lane = tid & 63;
    float2 v = *(const float2*)(s2 + bt * 128 + lane * 2);
    float w00 = lw[lane * 2], w01 = lw[lane * 2 + 1];
    float w10 = lw[128 + lane * 2], w11 = lw[128 + lane * 2 + 1];
    float a0 = v.x * w00 + v.y * w01;
    float a1 = v.x * w10 + v.y * w11;
    #pragma unroll
    for (int off = 32; off; off >>= 1) {
        a0 += __shfl_down(a0, off);
        a1 += __shfl_down(a1, off);
    }
    if (lane == 0) { out[bt * 2] = a0; out[bt * 2 + 1] = a1; }
}

extern "C" void kernel_launch(void* const* d_in, const int* in_sizes, int n_in,
                              void* d_out, int out_size, void* d_ws, size_t ws_size,
                              hipStream_t stream) {
    const float* x  = (const float*)d_in[0];   // [128,100,2,32,32]
    const float* w1 = (const float*)d_in[1];   // [4,2,5,5]
    const float* w2 = (const float*)d_in[2];   // [8,4,3,3]
    const float* lw = (const float*)d_in[3];   // [2,128]
    float* out = (float*)d_out;                // [128,100,2]

    float* ws   = (float*)d_ws;
    float* w1e  = ws;                          // 512 floats
    float* w2e  = ws + 512;                    // 512 floats
    float* y1   = ws + 1024;                   // 12800*256 floats = 13.1 MB
    float* s2g  = y1 + 3276800;                // 12800*128 floats = 6.55 MB

    prep_weights<<<4, 256, 0, stream>>>(w1, w2, w1e, w2e);
    conv1_pool<<<3200, 256, 0, stream>>>(x, w1e, y1);
    fused_wave<<<128, 64, 0, stream>>>(y1, w2e, s2g);
    linear_out<<<3200, 256, 0, stream>>>(s2g, lw, out);
}